// Round 4
// baseline (419.071 us; speedup 1.0000x reference)
//
#include <hip/hip_runtime.h>

#define DIM 144
#define ROWS 64
#define TILE_ELEMS (ROWS * DIM)        // 9216 floats per tile
#define TILE_F4 (TILE_ELEMS / 4)       // 2304 float4 per tile
#define NT 512                         // threads per block (8 waves)
#define F4PT 5                         // ceil(TILE_F4 / NT): threads<256 do 5, rest 4
#define PERSIST_BLOCKS 1024            // 4 blocks/CU on 256 CUs -> 32 waves/CU

// Workgroup barrier WITHOUT the vmcnt(0) drain that __syncthreads() emits.
// All three sync points have LDS-only dependencies -> lgkmcnt(0) suffices;
// prefetch loads stay in flight across barriers.
#define BARRIER_LGKM()                                            \
    do {                                                          \
        asm volatile("s_waitcnt lgkmcnt(0)" ::: "memory");        \
        __builtin_amdgcn_s_barrier();                             \
        asm volatile("" ::: "memory");                            \
    } while (0)

// ---------------------------------------------------------------------------
// Kernel 1: build Cw[9][16][16] — per-(l,t)-unit 16x16 mixing matrices.
// C[p][v][u] = mixing[k, i0, j0] * norm[i0, j0] * weight[k]
// ---------------------------------------------------------------------------
__global__ __launch_bounds__(256) void build_C(
    const float* __restrict__ weight,
    const float* __restrict__ mixing,
    const float* __restrict__ norm,
    float* __restrict__ Cw)
{
    int idx = blockIdx.x * 256 + threadIdx.x;   // 0 .. 2303
    if (idx >= 9 * 256) return;
    int p  = idx >> 8;          // unit 0..8
    int vu = idx & 255;
    int v = vu >> 4, u = vu & 15;
    int l, t, off;
    if (p == 0)      { l = 0; t = 0;     off = 0;  }
    else if (p < 4)  { l = 1; t = p - 1; off = 16; }
    else             { l = 2; t = p - 4; off = 64; }
    int d  = 2 * l + 1;
    int k  = l * 256 + v * 16 + u;
    int i0 = off + v * d + t;
    int j0 = off + u * d + t;
    float m  = mixing[(size_t)k * (DIM * DIM) + i0 * DIM + j0];
    float nc = norm[i0 * DIM + j0];
    Cw[idx] = m * nc * weight[k];
}

// ---------------------------------------------------------------------------
// Kernel 2: persistent transpose-mix-transpose at FULL occupancy.
// 512 threads (8 waves), 64-row tile, 36 KB LDS -> 4 blocks/CU = 32 waves/CU.
// Wave w computes units {w, w+8}. Single-tile register prefetch retained.
// LDS layout (XOR swizzle): addr(col,row) = col*64 + (row ^ (col>>2))
//   compute phase (lane=row): XOR bijection -> exactly 2 lanes/bank, free.
// ---------------------------------------------------------------------------
__device__ __forceinline__ void unit_params(int p, int& d, int& t, int& off) {
    int l;
    if (p == 0)      { l = 0; t = 0;     off = 0;  }
    else if (p < 4)  { l = 1; t = p - 1; off = 16; }
    else             { l = 2; t = p - 4; off = 64; }
    d = 2 * l + 1;
}

__device__ __forceinline__ void load_tile(
    const float4* __restrict__ feat4, long long base4, long long total4,
    int tid, float4 v[F4PT])
{
    if (base4 + TILE_F4 <= total4) {
#pragma unroll
        for (int i = 0; i < F4PT; ++i) {
            int e4 = i * NT + tid;
            if (e4 < TILE_F4) v[i] = feat4[base4 + e4];
        }
    } else {
#pragma unroll
        for (int i = 0; i < F4PT; ++i) {
            int e4 = i * NT + tid;
            long long g = base4 + e4;
            v[i] = (e4 < TILE_F4 && g < total4) ? feat4[g]
                                                : make_float4(0.f, 0.f, 0.f, 0.f);
        }
    }
}

__global__ __launch_bounds__(NT, 8) void tp_linear_kernel(
    const float4* __restrict__ feat4,
    const float* __restrict__ Cw,
    float4* __restrict__ out4,
    long long total4,
    int tiles)
{
    __shared__ float buf[DIM * 64];
    const int tid = threadIdx.x;
    const int nb  = gridDim.x;
    const int r   = tid & 63;
    const int w   = tid >> 6;          // wave 0..7

    int t = blockIdx.x;
    if (t >= tiles) return;

    float4 va[F4PT], vb[F4PT];
    load_tile(feat4, (long long)t * TILE_F4, total4, tid, va);

    for (; t < tiles; t += nb) {
        // ---- stage in: swizzled b32 LDS writes from prefetched registers ----
#pragma unroll
        for (int i = 0; i < F4PT; ++i) {
            int e4 = i * NT + tid;            // i=4 valid only for tid<256
            if (e4 < TILE_F4) {               // wave-uniform predicate
                int row = e4 / 36;
                int c   = e4 - row * 36;      // float4-column 0..35
                float* p = &buf[(4 * c) * 64 + (row ^ c)];
                p[0]   = va[i].x;
                p[64]  = va[i].y;
                p[128] = va[i].z;
                p[192] = va[i].w;
            }
        }

        // ---- issue next tile's loads; stay in flight across barriers ----
        int tn = t + nb;
        if (tn < tiles)
            load_tile(feat4, (long long)tn * TILE_F4, total4, tid, vb);

        BARRIER_LGKM();   // A: stage-in visible; vmcnt NOT drained

        // ---- compute: wave w owns units {w, w+8}; lane = row ----
        for (int p = w; p < 9; p += 8) {
            int d, tt, off;
            unit_params(p, d, tt, off);
            const float* __restrict__ C = Cw + p * 256;  // wave-uniform -> s_load

            float fin[16];
#pragma unroll
            for (int u = 0; u < 16; ++u) {
                int col = off + u * d + tt;
                fin[u] = buf[col * 64 + (r ^ (col >> 2))];
            }
            float acc[16];
#pragma unroll
            for (int vv = 0; vv < 16; ++vv) {
                float a = 0.0f;
#pragma unroll
                for (int u = 0; u < 16; ++u)
                    a += C[vv * 16 + u] * fin[u];
                acc[vv] = a;
            }
#pragma unroll
            for (int vv = 0; vv < 16; ++vv) {
                int col = off + vv * d + tt;
                buf[col * 64 + (r ^ (col >> 2))] = acc[vv];
            }
        }

        BARRIER_LGKM();   // B: compute writes visible before stage-out reads

        // ---- stage out: swizzled b32 LDS reads, coalesced float4 stores ----
        long long base4 = (long long)t * TILE_F4;
        bool full = (base4 + TILE_F4 <= total4);
#pragma unroll
        for (int i = 0; i < F4PT; ++i) {
            int e4 = i * NT + tid;
            if (e4 < TILE_F4) {
                int row = e4 / 36;
                int c   = e4 - row * 36;
                const float* p = &buf[(4 * c) * 64 + (row ^ c)];
                float4 o = make_float4(p[0], p[64], p[128], p[192]);
                if (full) {
                    out4[base4 + e4] = o;
                } else {
                    long long g = base4 + e4;
                    if (g < total4) out4[g] = o;
                }
            }
        }

        BARRIER_LGKM();   // C: stage-out reads done before buf overwrite

        // vb -> va; counted vmcnt wait for the prefetch lands here.
#pragma unroll
        for (int i = 0; i < F4PT; ++i) va[i] = vb[i];
    }
}

extern "C" void kernel_launch(void* const* d_in, const int* in_sizes, int n_in,
                              void* d_out, int out_size, void* d_ws, size_t ws_size,
                              hipStream_t stream)
{
    const float* feat   = (const float*)d_in[0];   // [B, 144]
    const float* weight = (const float*)d_in[1];   // [768]
    const float* mixing = (const float*)d_in[2];   // [768, 144, 144]
    const float* norm   = (const float*)d_in[3];   // [144, 144]
    float* out = (float*)d_out;
    float* Cw  = (float*)d_ws;                     // 9*256 floats

    long long total  = (long long)in_sizes[0];     // B * 144
    long long total4 = total / 4;                  // 144 % 4 == 0
    int nrows = (int)(total / DIM);
    int tiles = (nrows + ROWS - 1) / ROWS;
    int nb    = tiles < PERSIST_BLOCKS ? tiles : PERSIST_BLOCKS;

    build_C<<<9, 256, 0, stream>>>(weight, mixing, norm, Cw);
    tp_linear_kernel<<<nb, NT, 0, stream>>>(
        (const float4*)feat, Cw, (float4*)out, total4, tiles);
}

// Round 5
// 362.078 us; speedup vs baseline: 1.1574x; 1.1574x over previous
//
#include <hip/hip_runtime.h>

#define DIM 144
#define ROWS 64
#define TILE_ELEMS (ROWS * DIM)        // 9216 floats per tile
#define TILE_F4 (TILE_ELEMS / 4)       // 2304 float4 per tile
#define NT 512                         // threads per block (8 waves)
#define F4PT 5                         // ceil(TILE_F4/NT): tid<256 do 5, rest 4
#define PERSIST_BLOCKS 1024            // 4 blocks/CU on 256 CUs -> 32 waves/CU

// Workgroup barrier WITHOUT the vmcnt(0) drain of __syncthreads().
// All three sync points have LDS-only dependencies -> lgkmcnt(0) suffices.
#define BARRIER_LGKM()                                            \
    do {                                                          \
        asm volatile("s_waitcnt lgkmcnt(0)" ::: "memory");        \
        __builtin_amdgcn_s_barrier();                             \
        asm volatile("" ::: "memory");                            \
    } while (0)

// ---------------------------------------------------------------------------
// Kernel 1: build Cw[9][16][16] — per-(l,t)-unit 16x16 mixing matrices.
// C[p][v][u] = mixing[k, i0, j0] * norm[i0, j0] * weight[k]
// ---------------------------------------------------------------------------
__global__ __launch_bounds__(256) void build_C(
    const float* __restrict__ weight,
    const float* __restrict__ mixing,
    const float* __restrict__ norm,
    float* __restrict__ Cw)
{
    int idx = blockIdx.x * 256 + threadIdx.x;   // 0 .. 2303
    if (idx >= 9 * 256) return;
    int p  = idx >> 8;          // unit 0..8
    int vu = idx & 255;
    int v = vu >> 4, u = vu & 15;
    int l, t, off;
    if (p == 0)      { l = 0; t = 0;     off = 0;  }
    else if (p < 4)  { l = 1; t = p - 1; off = 16; }
    else             { l = 2; t = p - 4; off = 64; }
    int d  = 2 * l + 1;
    int k  = l * 256 + v * 16 + u;
    int i0 = off + v * d + t;
    int j0 = off + u * d + t;
    float m  = mixing[(size_t)k * (DIM * DIM) + i0 * DIM + j0];
    float nc = norm[i0 * DIM + j0];
    Cw[idx] = m * nc * weight[k];
}

// ---------------------------------------------------------------------------
// Kernel 2: persistent transpose-mix-transpose at full occupancy, register-
// lean. 512 threads (8 waves), 64-row tile, 36 KB LDS -> 4 blocks/CU =
// 32 waves/CU. No double-buffer prefetch (proven null r2/r3; caused the
// round-4 spill disaster under the 32-VGPR clamp). Compute streams each
// output scalar straight to LDS so peak live state is fin[16] + ~1.
// LDS layout (XOR swizzle): addr(col,row) = col*64 + (row ^ (col>>2))
//   compute phase (lane=row): XOR bijection -> exactly 2 lanes/bank, free.
// ---------------------------------------------------------------------------
__device__ __forceinline__ void unit_params(int p, int& d, int& t, int& off) {
    int l;
    if (p == 0)      { l = 0; t = 0;     off = 0;  }
    else if (p < 4)  { l = 1; t = p - 1; off = 16; }
    else             { l = 2; t = p - 4; off = 64; }
    d = 2 * l + 1;
}

__global__ __launch_bounds__(NT, 8) void tp_linear_kernel(
    const float4* __restrict__ feat4,
    const float* __restrict__ Cw,
    float4* __restrict__ out4,
    long long total4,
    int tiles)
{
    __shared__ float buf[DIM * 64];
    const int tid = threadIdx.x;
    const int nb  = gridDim.x;
    const int r   = tid & 63;
    const int w   = tid >> 6;          // wave 0..7

    for (int t = blockIdx.x; t < tiles; t += nb) {
        const long long base4 = (long long)t * TILE_F4;
        const bool full = (base4 + TILE_F4 <= total4);

        // ---- load tile: <=5 coalesced float4 per thread ----
        float4 va[F4PT];
        if (full) {
#pragma unroll
            for (int i = 0; i < F4PT; ++i) {
                int e4 = i * NT + tid;
                if (e4 < TILE_F4) va[i] = feat4[base4 + e4];
            }
        } else {
#pragma unroll
            for (int i = 0; i < F4PT; ++i) {
                int e4 = i * NT + tid;
                long long g = base4 + e4;
                va[i] = (e4 < TILE_F4 && g < total4)
                            ? feat4[g] : make_float4(0.f, 0.f, 0.f, 0.f);
            }
        }

        // ---- stage in: swizzled b32 LDS writes ----
#pragma unroll
        for (int i = 0; i < F4PT; ++i) {
            int e4 = i * NT + tid;            // i=4 valid only for tid<256
            if (e4 < TILE_F4) {               // wave-uniform predicate
                int row = e4 / 36;
                int c   = e4 - row * 36;      // float4-column 0..35
                float* p = &buf[(4 * c) * 64 + (row ^ c)];
                p[0]   = va[i].x;
                p[64]  = va[i].y;
                p[128] = va[i].z;
                p[192] = va[i].w;
            }
        }

        BARRIER_LGKM();   // A: stage-in ds_writes visible

        // ---- compute: wave w owns units {w, w+8}; lane = row ----
        // Streamed write-back: one accumulator scalar live at a time.
        // Safe vs. the fin reads: LDS ops from a wave to the same address
        // execute in program order, and all 16 ds_reads are issued (and
        // waited on for the first FMA chain) before the first ds_write.
        for (int p = w; p < 9; p += 8) {
            int d, tt, off;
            unit_params(p, d, tt, off);
            const float* __restrict__ C = Cw + p * 256;  // wave-uniform -> s_load

            float fin[16];
#pragma unroll
            for (int u = 0; u < 16; ++u) {
                int col = off + u * d + tt;
                fin[u] = buf[col * 64 + (r ^ (col >> 2))];
            }
#pragma unroll
            for (int vv = 0; vv < 16; ++vv) {
                float a = 0.0f;
#pragma unroll
                for (int u = 0; u < 16; ++u)
                    a += C[vv * 16 + u] * fin[u];
                int col = off + vv * d + tt;
                buf[col * 64 + (r ^ (col >> 2))] = a;
            }
        }

        BARRIER_LGKM();   // B: compute writes visible before stage-out reads

        // ---- stage out: swizzled b32 LDS reads, coalesced float4 stores ----
#pragma unroll
        for (int i = 0; i < F4PT; ++i) {
            int e4 = i * NT + tid;
            if (e4 < TILE_F4) {
                int row = e4 / 36;
                int c   = e4 - row * 36;
                const float* p = &buf[(4 * c) * 64 + (row ^ c)];
                float4 o = make_float4(p[0], p[64], p[128], p[192]);
                if (full) {
                    out4[base4 + e4] = o;
                } else {
                    long long g = base4 + e4;
                    if (g < total4) out4[g] = o;
                }
            }
        }

        BARRIER_LGKM();   // C: stage-out reads done before buf overwrite
    }
}

extern "C" void kernel_launch(void* const* d_in, const int* in_sizes, int n_in,
                              void* d_out, int out_size, void* d_ws, size_t ws_size,
                              hipStream_t stream)
{
    const float* feat   = (const float*)d_in[0];   // [B, 144]
    const float* weight = (const float*)d_in[1];   // [768]
    const float* mixing = (const float*)d_in[2];   // [768, 144, 144]
    const float* norm   = (const float*)d_in[3];   // [144, 144]
    float* out = (float*)d_out;
    float* Cw  = (float*)d_ws;                     // 9*256 floats

    long long total  = (long long)in_sizes[0];     // B * 144
    long long total4 = total / 4;                  // 144 % 4 == 0
    int nrows = (int)(total / DIM);
    int tiles = (nrows + ROWS - 1) / ROWS;
    int nb    = tiles < PERSIST_BLOCKS ? tiles : PERSIST_BLOCKS;

    build_C<<<9, 256, 0, stream>>>(weight, mixing, norm, Cw);
    tp_linear_kernel<<<nb, NT, 0, stream>>>(
        (const float4*)feat, Cw, (float4*)out, total4, tiles);
}

// Round 6
// 326.248 us; speedup vs baseline: 1.2845x; 1.1098x over previous
//
#include <hip/hip_runtime.h>

#define DIM 144
#define ROWS 64
#define TILE_ELEMS (ROWS * DIM)        // 9216 floats per tile
#define TILE_F4 (TILE_ELEMS / 4)       // 2304 float4 per tile
#define NT 512                         // threads per block (8 waves)
#define F4PT 5                         // ceil(TILE_F4/NT): tid<256 do 5, rest 4
#define PERSIST_BLOCKS 1024            // 4 blocks/CU on 256 CUs -> 32 waves/CU

// Workgroup barrier WITHOUT the vmcnt(0) drain of __syncthreads().
// All three sync points have LDS-only dependencies -> lgkmcnt(0) suffices.
#define BARRIER_LGKM()                                            \
    do {                                                          \
        asm volatile("s_waitcnt lgkmcnt(0)" ::: "memory");        \
        __builtin_amdgcn_s_barrier();                             \
        asm volatile("" ::: "memory");                            \
    } while (0)

// ---------------------------------------------------------------------------
// Kernel 1: build Cw[9][16][16] — per-(l,t)-unit 16x16 mixing matrices.
// C[p][v][u] = mixing[k, i0, j0] * norm[i0, j0] * weight[k]
// ---------------------------------------------------------------------------
__global__ __launch_bounds__(256) void build_C(
    const float* __restrict__ weight,
    const float* __restrict__ mixing,
    const float* __restrict__ norm,
    float* __restrict__ Cw)
{
    int idx = blockIdx.x * 256 + threadIdx.x;   // 0 .. 2303
    if (idx >= 9 * 256) return;
    int p  = idx >> 8;          // unit 0..8
    int vu = idx & 255;
    int v = vu >> 4, u = vu & 15;
    int l, t, off;
    if (p == 0)      { l = 0; t = 0;     off = 0;  }
    else if (p < 4)  { l = 1; t = p - 1; off = 16; }
    else             { l = 2; t = p - 4; off = 64; }
    int d  = 2 * l + 1;
    int k  = l * 256 + v * 16 + u;
    int i0 = off + v * d + t;
    int j0 = off + u * d + t;
    float m  = mixing[(size_t)k * (DIM * DIM) + i0 * DIM + j0];
    float nc = norm[i0 * DIM + j0];
    Cw[idx] = m * nc * weight[k];
}

// ---------------------------------------------------------------------------
// Kernel 2: persistent transpose-mix-transpose at full occupancy.
// 512 threads (8 waves), 64-row tile, 36 KB LDS -> 4 blocks/CU = 32 waves/CU
// (LDS is the occupancy binder). __launch_bounds__(512,4): observed compiler
// mapping cap=256/w gives a 64-VGPR budget -> kernel's ~40-50 live regs fit
// with ZERO scratch (the (512,8)=32-reg clamp caused 150-240 MB of spill
// traffic in rounds 4-5), and VGPR<=64 still admits 8 waves/SIMD.
// LDS layout (XOR swizzle): addr(col,row) = col*64 + (row ^ (col>>2))
//   compute phase (lane=row): XOR bijection -> exactly 2 lanes/bank, free.
// ---------------------------------------------------------------------------
__device__ __forceinline__ void unit_params(int p, int& d, int& t, int& off) {
    int l;
    if (p == 0)      { l = 0; t = 0;     off = 0;  }
    else if (p < 4)  { l = 1; t = p - 1; off = 16; }
    else             { l = 2; t = p - 4; off = 64; }
    d = 2 * l + 1;
}

__global__ __launch_bounds__(NT, 4) void tp_linear_kernel(
    const float4* __restrict__ feat4,
    const float* __restrict__ Cw,
    float4* __restrict__ out4,
    long long total4,
    int tiles)
{
    __shared__ float buf[DIM * 64];
    const int tid = threadIdx.x;
    const int nb  = gridDim.x;
    const int r   = tid & 63;
    const int w   = tid >> 6;          // wave 0..7

    for (int t = blockIdx.x; t < tiles; t += nb) {
        const long long base4 = (long long)t * TILE_F4;
        const bool full = (base4 + TILE_F4 <= total4);

        // ---- load tile: <=5 coalesced float4 per thread ----
        float4 va[F4PT];
        if (full) {
#pragma unroll
            for (int i = 0; i < F4PT; ++i) {
                int e4 = i * NT + tid;
                if (e4 < TILE_F4) va[i] = feat4[base4 + e4];
            }
        } else {
#pragma unroll
            for (int i = 0; i < F4PT; ++i) {
                int e4 = i * NT + tid;
                long long g = base4 + e4;
                va[i] = (e4 < TILE_F4 && g < total4)
                            ? feat4[g] : make_float4(0.f, 0.f, 0.f, 0.f);
            }
        }

        // ---- stage in: swizzled b32 LDS writes ----
#pragma unroll
        for (int i = 0; i < F4PT; ++i) {
            int e4 = i * NT + tid;            // i=4 valid only for tid<256
            if (e4 < TILE_F4) {               // wave-uniform predicate
                int row = e4 / 36;
                int c   = e4 - row * 36;      // float4-column 0..35
                float* p = &buf[(4 * c) * 64 + (row ^ c)];
                p[0]   = va[i].x;
                p[64]  = va[i].y;
                p[128] = va[i].z;
                p[192] = va[i].w;
            }
        }

        BARRIER_LGKM();   // A: stage-in ds_writes visible

        // ---- compute: wave w owns units {w, w+8}; lane = row ----
        // Streamed write-back: one accumulator scalar live at a time.
        for (int p = w; p < 9; p += 8) {
            int d, tt, off;
            unit_params(p, d, tt, off);
            const float* __restrict__ C = Cw + p * 256;  // wave-uniform -> s_load

            float fin[16];
#pragma unroll
            for (int u = 0; u < 16; ++u) {
                int col = off + u * d + tt;
                fin[u] = buf[col * 64 + (r ^ (col >> 2))];
            }
#pragma unroll
            for (int vv = 0; vv < 16; ++vv) {
                float a = 0.0f;
#pragma unroll
                for (int u = 0; u < 16; ++u)
                    a += C[vv * 16 + u] * fin[u];
                int col = off + vv * d + tt;
                buf[col * 64 + (r ^ (col >> 2))] = a;
            }
        }

        BARRIER_LGKM();   // B: compute writes visible before stage-out reads

        // ---- stage out: swizzled b32 LDS reads, coalesced float4 stores ----
#pragma unroll
        for (int i = 0; i < F4PT; ++i) {
            int e4 = i * NT + tid;
            if (e4 < TILE_F4) {
                int row = e4 / 36;
                int c   = e4 - row * 36;
                const float* p = &buf[(4 * c) * 64 + (row ^ c)];
                float4 o = make_float4(p[0], p[64], p[128], p[192]);
                if (full) {
                    out4[base4 + e4] = o;
                } else {
                    long long g = base4 + e4;
                    if (g < total4) out4[g] = o;
                }
            }
        }

        BARRIER_LGKM();   // C: stage-out reads done before buf overwrite
    }
}

extern "C" void kernel_launch(void* const* d_in, const int* in_sizes, int n_in,
                              void* d_out, int out_size, void* d_ws, size_t ws_size,
                              hipStream_t stream)
{
    const float* feat   = (const float*)d_in[0];   // [B, 144]
    const float* weight = (const float*)d_in[1];   // [768]
    const float* mixing = (const float*)d_in[2];   // [768, 144, 144]
    const float* norm   = (const float*)d_in[3];   // [144, 144]
    float* out = (float*)d_out;
    float* Cw  = (float*)d_ws;                     // 9*256 floats

    long long total  = (long long)in_sizes[0];     // B * 144
    long long total4 = total / 4;                  // 144 % 4 == 0
    int nrows = (int)(total / DIM);
    int tiles = (nrows + ROWS - 1) / ROWS;
    int nb    = tiles < PERSIST_BLOCKS ? tiles : PERSIST_BLOCKS;

    build_C<<<9, 256, 0, stream>>>(weight, mixing, norm, Cw);
    tp_linear_kernel<<<nb, NT, 0, stream>>>(
        (const float4*)feat, Cw, (float4*)out, total4, tiles);
}

// Round 7
// 324.935 us; speedup vs baseline: 1.2897x; 1.0040x over previous
//
#include <hip/hip_runtime.h>

#define DIM 144
#define ROWS 64
#define TILE_ELEMS (ROWS * DIM)        // 9216 floats per tile
#define TILE_F4 (TILE_ELEMS / 4)       // 2304 float4 per tile
#define NT 512                         // threads per block (8 waves)
#define F4PT 5                         // ceil(TILE_F4/NT): tid<256 do 5, rest 4
#define PERSIST_BLOCKS 1024            // 4 blocks/CU on 256 CUs -> 32 waves/CU

// Workgroup barrier WITHOUT the vmcnt(0) drain of __syncthreads().
// All three sync points have LDS-only dependencies -> lgkmcnt(0) suffices.
#define BARRIER_LGKM()                                            \
    do {                                                          \
        asm volatile("s_waitcnt lgkmcnt(0)" ::: "memory");        \
        __builtin_amdgcn_s_barrier();                             \
        asm volatile("" ::: "memory");                            \
    } while (0)

// ---------------------------------------------------------------------------
// Kernel 1: build Cw[9][16][16] — per-(l,t)-unit 16x16 mixing matrices.
// C[p][v][u] = mixing[k, i0, j0] * norm[i0, j0] * weight[k]
// ---------------------------------------------------------------------------
__global__ __launch_bounds__(256) void build_C(
    const float* __restrict__ weight,
    const float* __restrict__ mixing,
    const float* __restrict__ norm,
    float* __restrict__ Cw)
{
    int idx = blockIdx.x * 256 + threadIdx.x;   // 0 .. 2303
    if (idx >= 9 * 256) return;
    int p  = idx >> 8;          // unit 0..8
    int vu = idx & 255;
    int v = vu >> 4, u = vu & 15;
    int l, t, off;
    if (p == 0)      { l = 0; t = 0;     off = 0;  }
    else if (p < 4)  { l = 1; t = p - 1; off = 16; }
    else             { l = 2; t = p - 4; off = 64; }
    int d  = 2 * l + 1;
    int k  = l * 256 + v * 16 + u;
    int i0 = off + v * d + t;
    int j0 = off + u * d + t;
    float m  = mixing[(size_t)k * (DIM * DIM) + i0 * DIM + j0];
    float nc = norm[i0 * DIM + j0];
    Cw[idx] = m * nc * weight[k];
}

// ---------------------------------------------------------------------------
// Kernel 2: persistent transpose-mix-transpose.
// 512 threads (8 waves), 64-row tile, 36 KB LDS -> 4 blocks/CU = 32 waves/CU
// (LDS is the intended occupancy binder).
// __launch_bounds__(NT) ONLY — observed on this toolchain that the 2nd arg w
// acts as BOTH a VGPR budget (256/w) and a residency cap (~w waves/EU):
//   (512,8): VGPR 32 -> spills (r4/r5, +150-240 MB scratch traffic)
//   (512,4): VGPR 56, clean, but residency capped ~2 blocks/CU (r6, occ 39%)
// One-arg form: compiler picked 56 VGPR under the relaxed cap (r6) which
// admits 8 waves/SIMD; no attribute残 cap -> HW should reside 4 blocks/CU.
// LDS layout (XOR swizzle): addr(col,row) = col*64 + (row ^ (col>>2))
//   compute phase (lane=row): XOR bijection -> exactly 2 lanes/bank, free.
// ---------------------------------------------------------------------------
__device__ __forceinline__ void unit_params(int p, int& d, int& t, int& off) {
    int l;
    if (p == 0)      { l = 0; t = 0;     off = 0;  }
    else if (p < 4)  { l = 1; t = p - 1; off = 16; }
    else             { l = 2; t = p - 4; off = 64; }
    d = 2 * l + 1;
}

__global__ __launch_bounds__(NT) void tp_linear_kernel(
    const float4* __restrict__ feat4,
    const float* __restrict__ Cw,
    float4* __restrict__ out4,
    long long total4,
    int tiles)
{
    __shared__ float buf[DIM * 64];
    const int tid = threadIdx.x;
    const int nb  = gridDim.x;
    const int r   = tid & 63;
    const int w   = tid >> 6;          // wave 0..7

    for (int t = blockIdx.x; t < tiles; t += nb) {
        const long long base4 = (long long)t * TILE_F4;
        const bool full = (base4 + TILE_F4 <= total4);

        // ---- load tile: <=5 coalesced float4 per thread ----
        float4 va[F4PT];
        if (full) {
#pragma unroll
            for (int i = 0; i < F4PT; ++i) {
                int e4 = i * NT + tid;
                if (e4 < TILE_F4) va[i] = feat4[base4 + e4];
            }
        } else {
#pragma unroll
            for (int i = 0; i < F4PT; ++i) {
                int e4 = i * NT + tid;
                long long g = base4 + e4;
                va[i] = (e4 < TILE_F4 && g < total4)
                            ? feat4[g] : make_float4(0.f, 0.f, 0.f, 0.f);
            }
        }

        // ---- stage in: swizzled b32 LDS writes ----
#pragma unroll
        for (int i = 0; i < F4PT; ++i) {
            int e4 = i * NT + tid;            // i=4 valid only for tid<256
            if (e4 < TILE_F4) {               // wave-uniform predicate
                int row = e4 / 36;
                int c   = e4 - row * 36;      // float4-column 0..35
                float* p = &buf[(4 * c) * 64 + (row ^ c)];
                p[0]   = va[i].x;
                p[64]  = va[i].y;
                p[128] = va[i].z;
                p[192] = va[i].w;
            }
        }

        BARRIER_LGKM();   // A: stage-in ds_writes visible

        // ---- compute: wave w owns units {w, w+8}; lane = row ----
        // Streamed write-back: one accumulator scalar live at a time.
        for (int p = w; p < 9; p += 8) {
            int d, tt, off;
            unit_params(p, d, tt, off);
            const float* __restrict__ C = Cw + p * 256;  // wave-uniform -> s_load

            float fin[16];
#pragma unroll
            for (int u = 0; u < 16; ++u) {
                int col = off + u * d + tt;
                fin[u] = buf[col * 64 + (r ^ (col >> 2))];
            }
#pragma unroll
            for (int vv = 0; vv < 16; ++vv) {
                float a = 0.0f;
#pragma unroll
                for (int u = 0; u < 16; ++u)
                    a += C[vv * 16 + u] * fin[u];
                int col = off + vv * d + tt;
                buf[col * 64 + (r ^ (col >> 2))] = a;
            }
        }

        BARRIER_LGKM();   // B: compute writes visible before stage-out reads

        // ---- stage out: swizzled b32 LDS reads, coalesced float4 stores ----
#pragma unroll
        for (int i = 0; i < F4PT; ++i) {
            int e4 = i * NT + tid;
            if (e4 < TILE_F4) {
                int row = e4 / 36;
                int c   = e4 - row * 36;
                const float* p = &buf[(4 * c) * 64 + (row ^ c)];
                float4 o = make_float4(p[0], p[64], p[128], p[192]);
                if (full) {
                    out4[base4 + e4] = o;
                } else {
                    long long g = base4 + e4;
                    if (g < total4) out4[g] = o;
                }
            }
        }

        BARRIER_LGKM();   // C: stage-out reads done before buf overwrite
    }
}

extern "C" void kernel_launch(void* const* d_in, const int* in_sizes, int n_in,
                              void* d_out, int out_size, void* d_ws, size_t ws_size,
                              hipStream_t stream)
{
    const float* feat   = (const float*)d_in[0];   // [B, 144]
    const float* weight = (const float*)d_in[1];   // [768]
    const float* mixing = (const float*)d_in[2];   // [768, 144, 144]
    const float* norm   = (const float*)d_in[3];   // [144, 144]
    float* out = (float*)d_out;
    float* Cw  = (float*)d_ws;                     // 9*256 floats

    long long total  = (long long)in_sizes[0];     // B * 144
    long long total4 = total / 4;                  // 144 % 4 == 0
    int nrows = (int)(total / DIM);
    int tiles = (nrows + ROWS - 1) / ROWS;
    int nb    = tiles < PERSIST_BLOCKS ? tiles : PERSIST_BLOCKS;

    build_C<<<9, 256, 0, stream>>>(weight, mixing, norm, Cw);
    tp_linear_kernel<<<nb, NT, 0, stream>>>(
        (const float4*)feat, Cw, (float4*)out, total4, tiles);
}